// Round 1
// baseline (152.825 us; speedup 1.0000x reference)
//
#include <hip/hip_runtime.h>

constexpr int NRAYS = 131072;
constexpr int S = 192;
constexpr float DELTA_INF_F = 1e10f;
constexpr float EPS_F = 1e-10f;

// One 64-lane wave per ray; lane l owns samples [3l, 3l+2].
__global__ __launch_bounds__(256) void nerf_render_kernel(
    const float* __restrict__ ray_samples,  // [N,S,3]
    const float* __restrict__ densities,    // [N,S]
    const float* __restrict__ rgb,          // [N,S,3]
    const float* __restrict__ bg,           // [3]
    float* __restrict__ out_rgb,            // [N,3]
    float* __restrict__ out_acc,            // [N]
    float* __restrict__ out_w)              // [N,S]
{
    const int lane = threadIdx.x & 63;
    const int ray  = (blockIdx.x << 2) + (threadIdx.x >> 6);

    const size_t rbase = (size_t)ray * S;

    // ---- positions: 9 contiguous floats per lane (3 samples x xyz) ----
    const float* rs = ray_samples + rbase * 3 + lane * 9;
    float p[9];
#pragma unroll
    for (int j = 0; j < 9; ++j) p[j] = rs[j];

    // next sample's xyz comes from lane+1's first sample
    float xn = __shfl_down(p[0], 1);
    float yn = __shfl_down(p[1], 1);
    float zn = __shfl_down(p[2], 1);

    float dx = p[3] - p[0], dy = p[4] - p[1], dz = p[5] - p[2];
    float d0 = sqrtf(dx*dx + dy*dy + dz*dz);
    dx = p[6] - p[3]; dy = p[7] - p[4]; dz = p[8] - p[5];
    float d1 = sqrtf(dx*dx + dy*dy + dz*dz);
    float d2 = DELTA_INF_F;                 // last sample of the ray
    if (lane < 63) {
        dx = xn - p[6]; dy = yn - p[7]; dz = zn - p[8];
        d2 = sqrtf(dx*dx + dy*dy + dz*dz);
    }

    // ---- densities: 3 contiguous floats per lane ----
    const float* dn = densities + rbase + lane * 3;
    float e0 = expf(-fmaxf(dn[0], 0.0f) * d0);
    float e1 = expf(-fmaxf(dn[1], 0.0f) * d1);
    float e2 = expf(-fmaxf(dn[2], 0.0f) * d2);

    // mirror reference algebra: alpha = 1-e ; t = (1-alpha) + eps
    float a0 = 1.0f - e0, a1 = 1.0f - e1, a2 = 1.0f - e2;
    float t0 = (1.0f - a0) + EPS_F;
    float t1 = (1.0f - a1) + EPS_F;
    float t2 = (1.0f - a2) + EPS_F;

    // ---- exclusive cumprod across the ray ----
    float P = t0 * t1 * t2;              // this lane's total product
    float incl = P;
#pragma unroll
    for (int off = 1; off < 64; off <<= 1) {
        float t = __shfl_up(incl, off);
        if (lane >= off) incl *= t;
    }
    float pref = __shfl_up(incl, 1);     // exclusive prefix across lanes
    if (lane == 0) pref = 1.0f;

    float w0 = a0 * pref;
    float w1 = a1 * pref * t0;
    float w2 = a2 * pref * t0 * t1;

    // ---- write weights ----
    float* wout = out_w + rbase + lane * 3;
    wout[0] = w0; wout[1] = w1; wout[2] = w2;

    // ---- weighted rgb + alpha sums ----
    const float* cg = rgb + rbase * 3 + lane * 9;
    float cr = w0*cg[0] + w1*cg[3] + w2*cg[6];
    float cgrn = w0*cg[1] + w1*cg[4] + w2*cg[7];
    float cb = w0*cg[2] + w1*cg[5] + w2*cg[8];
    float acc = w0 + w1 + w2;

#pragma unroll
    for (int off = 32; off >= 1; off >>= 1) {
        cr   += __shfl_xor(cr, off);
        cgrn += __shfl_xor(cgrn, off);
        cb   += __shfl_xor(cb, off);
        acc  += __shfl_xor(acc, off);
    }

    if (lane == 0) {
        float om = 1.0f - acc;
        out_rgb[(size_t)ray*3 + 0] = cr   + bg[0] * om;
        out_rgb[(size_t)ray*3 + 1] = cgrn + bg[1] * om;
        out_rgb[(size_t)ray*3 + 2] = cb   + bg[2] * om;
        out_acc[ray] = acc;
    }
}

extern "C" void kernel_launch(void* const* d_in, const int* in_sizes, int n_in,
                              void* d_out, int out_size, void* d_ws, size_t ws_size,
                              hipStream_t stream) {
    const float* ray_samples = (const float*)d_in[0];
    const float* densities   = (const float*)d_in[1];
    const float* rgb         = (const float*)d_in[2];
    const float* bg          = (const float*)d_in[3];

    float* o = (float*)d_out;
    float* out_rgb = o;                                    // N*3
    float* out_acc = o + (size_t)NRAYS * 3;                // N
    float* out_w   = o + (size_t)NRAYS * 3 + NRAYS;        // N*S

    dim3 grid(NRAYS / 4), block(256);
    hipLaunchKernelGGL(nerf_render_kernel, grid, block, 0, stream,
                       ray_samples, densities, rgb, bg, out_rgb, out_acc, out_w);
}